// Round 1
// baseline (67.975 us; speedup 1.0000x reference)
//
#include <hip/hip_runtime.h>

#define NN 16
#define CC 16
#define HH 52
#define WW 52
#define KKN 9           // 3x3 kernel positions
#define OO 16
#define INV_L2 (1.0f / 22500.0f)   // 1/(KK*L) = 1/(9*2500)

// Stage 1: per (n,c) image, compute T[kk] = sum over shifted 50x50 window,
// Q[kk] = sum of squares over same window. kk = i*3+j, window rows [i, i+50),
// cols [j, j+50).
__global__ __launch_bounds__(64) void tvar_stage1(const float* __restrict__ x,
                                                  float* __restrict__ T,
                                                  float* __restrict__ Q) {
    __shared__ float img[HH * WW];          // 10816 B
    __shared__ float R[6][HH];              // R0,R1,R2 (win row sums), R20,R21,R22 (sq)
    __shared__ float colfull[6], e0[6], e1[6], e50[6], e51[6];

    const int nc = blockIdx.x;              // n*16 + c
    const int t  = threadIdx.x;

    // Coalesced float4 stage of the 52x52 image (2704 floats = 676 float4)
    const float4* src = (const float4*)(x + nc * (HH * WW));
    float4* dst = (float4*)img;
    for (int i = t; i < (HH * WW) / 4; i += 64) dst[i] = src[i];
    __syncthreads();

    // Per-row full sums + edge corrections -> 3 windowed sums (cols j..j+49)
    if (t < HH) {
        const float* row = img + t * WW;
        float s = 0.f, s2 = 0.f;
        #pragma unroll
        for (int xc = 0; xc < WW; ++xc) { float v = row[xc]; s += v; s2 += v * v; }
        const float a0 = row[0], a1 = row[1], a50 = row[50], a51 = row[51];
        R[0][t] = s  - a50 - a51;            // cols 0..49
        R[1][t] = s  - a0  - a51;            // cols 1..50
        R[2][t] = s  - a0  - a1;             // cols 2..51
        R[3][t] = s2 - a50 * a50 - a51 * a51;
        R[4][t] = s2 - a0  * a0  - a51 * a51;
        R[5][t] = s2 - a0  * a0  - a1  * a1;
    }
    __syncthreads();

    // Column reduce each of the 6 arrays over all 52 rows; keep edges
    if (t < 6) {
        float s = 0.f;
        for (int r = 0; r < HH; ++r) s += R[t][r];
        colfull[t] = s;
        e0[t] = R[t][0]; e1[t] = R[t][1]; e50[t] = R[t][50]; e51[t] = R[t][51];
    }
    __syncthreads();

    // T[(i,j)] = sum rows i..i+49 of R[j]; same for Q with R[3+j]
    if (t < KKN) {
        const int i = t / 3, j = t % 3;
        const float c1 = (i == 0) ? (e50[j] + e51[j])
                       : (i == 1) ? (e0[j]  + e51[j])
                                  : (e0[j]  + e1[j]);
        T[nc * KKN + t] = colfull[j] - c1;
        const float c2 = (i == 0) ? (e50[3 + j] + e51[3 + j])
                       : (i == 1) ? (e0[3 + j]  + e51[3 + j])
                                  : (e0[3 + j]  + e1[3 + j]);
        Q[nc * KKN + t] = colfull[3 + j] - c2;
    }
}

// Stage 2: out[n,o] = sum_c ( sum_kk W^2*Q - (sum_kk W*T)^2/22500 ) / (sum_kk W)
// final[i, n, o] = out[n, o] + B[i, n]   (i over O, broadcast)
__global__ __launch_bounds__(256) void tvar_stage2(const float* __restrict__ Wt,
                                                   const float* __restrict__ B,
                                                   const float* __restrict__ T,
                                                   const float* __restrict__ Q,
                                                   float* __restrict__ out) {
    __shared__ float sW[OO * CC * KKN];     // 2304
    __shared__ float sT[NN * CC * KKN];     // 2304
    __shared__ float sQ[NN * CC * KKN];     // 2304

    const int t = threadIdx.x;              // t = n*16 + o
    for (int i = t; i < OO * CC * KKN; i += 256) {
        sW[i] = Wt[i];
        sT[i] = T[i];
        sQ[i] = Q[i];
    }
    __syncthreads();

    const int n = t >> 4;
    const int o = t & 15;

    float acc = 0.f;
    #pragma unroll
    for (int c = 0; c < CC; ++c) {
        const float* w = sW + (o * CC + c) * KKN;
        const float* tt = sT + (n * CC + c) * KKN;
        const float* qq = sQ + (n * CC + c) * KKN;
        float size = 0.f, s1 = 0.f, sq = 0.f;
        #pragma unroll
        for (int k = 0; k < KKN; ++k) {
            const float wv = w[k];
            size += wv;
            s1   += wv * tt[k];
            sq   += wv * wv * qq[k];
        }
        acc += (sq - s1 * s1 * INV_L2) / size;
    }

    // Broadcast-add bias: out[i*256 + n*16 + o] = acc + B[i*16 + n]
    #pragma unroll
    for (int i = 0; i < OO; ++i) {
        out[i * 256 + t] = acc + B[i * CC + n];
    }
}

extern "C" void kernel_launch(void* const* d_in, const int* in_sizes, int n_in,
                              void* d_out, int out_size, void* d_ws, size_t ws_size,
                              hipStream_t stream) {
    const float* x  = (const float*)d_in[0];
    const float* Wt = (const float*)d_in[1];
    const float* B  = (const float*)d_in[2];
    float* out = (float*)d_out;

    float* T = (float*)d_ws;                         // 2304 floats
    float* Q = T + NN * CC * KKN;                    // 2304 floats

    tvar_stage1<<<NN * CC, 64, 0, stream>>>(x, T, Q);
    tvar_stage2<<<1, 256, 0, stream>>>(Wt, B, T, Q, out);
}